// Round 17
// baseline (484.530 us; speedup 1.0000x reference)
//
#include <hip/hip_runtime.h>
#include <hip/hip_bf16.h>

typedef __attribute__((ext_vector_type(8))) short short8;
typedef __attribute__((ext_vector_type(4))) short s16x4;
typedef __attribute__((ext_vector_type(4))) float f32x4;
typedef unsigned short u16;

#define DEV __device__ __forceinline__
#define MFMA32(a, b, c) __builtin_amdgcn_mfma_f32_16x16x32_bf16(a, b, c, 0, 0, 0)
#define MFMA16(a, b, c) __builtin_amdgcn_mfma_f32_16x16x16bf16_1k(a, b, c, 0, 0, 0)
#define SBAR() asm volatile("s_barrier" ::: "memory")

DEV u16 f2b(float f) {
    __hip_bfloat16 h = __float2bfloat16(f);
    return __builtin_bit_cast(unsigned short, h);
}

DEV void gl_lds16(const u16* g, u16* l) {
    __builtin_amdgcn_global_load_lds((const unsigned int*)g, (unsigned int*)l, 16, 0, 0);
}

// ---------------- cast x: fp32 -> bf16 ----------------
__global__ __launch_bounds__(256) void cast_bf16(const float* __restrict__ in, u16* __restrict__ out, int n) {
    int i = (blockIdx.x * 256 + threadIdx.x) * 4;
    if (i < n) {
        float4 v = *(const float4*)(in + i);
        ushort4 o;
        o.x = f2b(v.x); o.y = f2b(v.y); o.z = f2b(v.z); o.w = f2b(v.w);
        *(ushort4*)(out + i) = o;
    }
}

// ---------------- transpose + cast: W[R][C] fp32 -> Wt[C][R] bf16 ----------------
__global__ __launch_bounds__(256) void transpose_cast(const float* __restrict__ in, u16* __restrict__ out,
                                                      int R, int C) {
    __shared__ float t[32][33];
    int bx = blockIdx.x * 32;
    int by = blockIdx.y * 32;
    int tx = threadIdx.x, ty = threadIdx.y;  // (32, 8)
#pragma unroll
    for (int i = 0; i < 32; i += 8) t[ty + i][tx] = in[(size_t)(by + ty + i) * C + bx + tx];
    __syncthreads();
#pragma unroll
    for (int i = 0; i < 32; i += 8) out[(size_t)(bx + ty + i) * R + by + tx] = f2b(t[tx][ty + i]);
}

// ---------------- batched 1024x1024 transpose + cast (4 matrices in one launch) ----------------
__global__ __launch_bounds__(256) void transpose_cast4(const float* __restrict__ w0, const float* __restrict__ w1,
                                                       const float* __restrict__ w2, const float* __restrict__ w3,
                                                       u16* __restrict__ o0, u16* __restrict__ o1,
                                                       u16* __restrict__ o2, u16* __restrict__ o3) {
    const float* in = (blockIdx.z == 0) ? w0 : (blockIdx.z == 1) ? w1 : (blockIdx.z == 2) ? w2 : w3;
    u16* out = (blockIdx.z == 0) ? o0 : (blockIdx.z == 1) ? o1 : (blockIdx.z == 2) ? o2 : o3;
    __shared__ float t[32][33];
    int bx = blockIdx.x * 32;
    int by = blockIdx.y * 32;
    int tx = threadIdx.x, ty = threadIdx.y;  // (32, 8)
#pragma unroll
    for (int i = 0; i < 32; i += 8) t[ty + i][tx] = in[(size_t)(by + ty + i) * 1024 + bx + tx];
    __syncthreads();
#pragma unroll
    for (int i = 0; i < 32; i += 8) out[(size_t)(bx + ty + i) * 1024 + by + tx] = f2b(t[tx][ty + i]);
}

// ---------------- pack biases into one buffer ----------------
__global__ __launch_bounds__(256) void pack_bias(const float* __restrict__ bq, const float* __restrict__ bk,
                                                 const float* __restrict__ bv, const float* __restrict__ bo,
                                                 const float* __restrict__ b1, const float* __restrict__ b2,
                                                 float* __restrict__ out) {
    int i = blockIdx.x * 256 + threadIdx.x;
    if (i >= 9216) return;
    float v;
    if (i < 1024) v = bq[i];
    else if (i < 2048) v = bk[i - 1024];
    else if (i < 3072) v = bv[i - 2048];
    else if (i < 4096) v = bo[i - 3072];
    else if (i < 8192) v = b1[i - 4096];
    else v = b2[i - 8192];
    out[i] = v;
}

// ---------------- GEMM: C[M][N] = A[M][K] * Bt[N][K]^T + bias (+res), optional GELU ----------------
// m97 2-barrier structure, BK=64, BMx128 tile, 256 threads (4 waves, 2x2), G4 XOR swizzle
// both-sides. XCD-aware block swizzle: each XCD gets a contiguous bx-major chunk of the
// linearized grid -> neighboring blocks share A/B panels in the same per-XCD L2.
template <int BM, bool GELU, bool BF16OUT, bool RESID>
__global__ __launch_bounds__(256) void gemm_bt(const u16* __restrict__ A, const u16* __restrict__ B,
                                               const float* __restrict__ bias, float* __restrict__ cf,
                                               u16* __restrict__ cb, const float* __restrict__ res,
                                               int M, int N, int K) {
    constexpr int MI = BM / 32;   // per-wave M fragments (4 or 2)
    __shared__ __align__(16) u16 As[BM * 64];
    __shared__ __align__(16) u16 Bs[128 * 64];
    const int tid = threadIdx.x;
    const int wid = tid >> 6, lane = tid & 63;
    const int wr = wid >> 1, wc = wid & 1;
    const int r16 = lane & 15, g = lane >> 4;
    const int sw = r16 & 7;

    // XCD swizzle (grid divisible by 8): XCD k gets linear ids [k*cpx, (k+1)*cpx)
    const int nwg = gridDim.x * gridDim.y;
    const int id = blockIdx.y * gridDim.x + blockIdx.x;
    const int sid = (id & 7) * (nwg >> 3) + (id >> 3);
    const int m0 = (sid % gridDim.x) * BM, n0 = (sid / gridDim.x) * 128;

    f32x4 acc[MI][4];
#pragma unroll
    for (int i = 0; i < MI; i++)
#pragma unroll
        for (int j = 0; j < 4; j++) acc[i][j] = (f32x4){0.f, 0.f, 0.f, 0.f};

    const int srow = tid >> 3;
    const int schunk = (tid & 7) ^ (srow & 7);
    const u16* ga = A + (size_t)(m0 + srow) * K + schunk * 8;
    const u16* gb = B + (size_t)(n0 + srow) * K + schunk * 8;

    for (int kt = 0; kt < K; kt += 64) {
#pragma unroll
        for (int j = 0; j < BM / 32; j++)
            gl_lds16(ga + (size_t)(j * 32) * K + kt, &As[(j * 32 + wid * 8) * 64]);
#pragma unroll
        for (int j = 0; j < 4; j++)
            gl_lds16(gb + (size_t)(j * 32) * K + kt, &Bs[(j * 32 + wid * 8) * 64]);
        __syncthreads();
#pragma unroll
        for (int ks = 0; ks < 2; ks++) {
            short8 af[MI], bfr[4];
#pragma unroll
            for (int i = 0; i < MI; i++) {
                int row = wr * (BM / 2) + i * 16 + r16;
                af[i] = *(const short8*)((const char*)As + row * 128 + (((ks * 4 + g) ^ sw) * 16));
            }
#pragma unroll
            for (int j = 0; j < 4; j++) {
                int row = wc * 64 + j * 16 + r16;
                bfr[j] = *(const short8*)((const char*)Bs + row * 128 + (((ks * 4 + g) ^ sw) * 16));
            }
#pragma unroll
            for (int i = 0; i < MI; i++)
#pragma unroll
                for (int j = 0; j < 4; j++) acc[i][j] = MFMA32(af[i], bfr[j], acc[i][j]);
        }
        __syncthreads();
    }

#pragma unroll
    for (int i = 0; i < MI; i++) {
#pragma unroll
        for (int j = 0; j < 4; j++) {
#pragma unroll
            for (int r = 0; r < 4; r++) {
                int row = m0 + wr * (BM / 2) + i * 16 + g * 4 + r;
                int col = n0 + wc * 64 + j * 16 + r16;
                float v = acc[i][j][r] + bias[col];
                if (RESID) v += res[(size_t)row * N + col];
                if (GELU) v = 0.5f * v * (1.0f + erff(v * 0.70710678118654752f));
                if (BF16OUT) cb[(size_t)row * N + col] = f2b(v);
                else cf[(size_t)row * N + col] = v;
            }
        }
    }
}

// ---------------- flash attention (swapped-QK^T, KBLK=64, 2 q-groups/wave, dbuf K/V) ----------------
// Static-shift softmax (no running max; logits bounded). Double-buffered K/V, counted vmcnt(4).
// 1-D grid 1024, XCD-swizzled so the 16 q-blocks of one (b,h) share one XCD's L2 K/V panel.
__global__ __launch_bounds__(256, 4) void attn_kernel(const u16* __restrict__ qkv, const int* __restrict__ mask,
                                                      u16* __restrict__ ctx) {
    const int tid = threadIdx.x, wid = tid >> 6, lane = tid & 63;
    const int r16 = lane & 15, g = lane >> 4;
    const int id = blockIdx.x;
    const int sid = (id & 7) * 128 + (id >> 3);   // XCD k gets sids [128k, 128k+128)
    const int h = (sid >> 4) & 15, b = sid >> 8;
    const size_t baserow = (size_t)b * 2048;
    const int q0 = (sid & 15) * 128;

    __shared__ __align__(16) u16 Ks[2][64 * 64];
    __shared__ __align__(16) u16 Vs[2][64 * 64];
    __shared__ unsigned tflags_sh;

    const float SCALE = 0.18033688011112042f;   // 0.125 * log2(e)
    const float MNEG = -6.196328018e9f;         // -2^32 * log2(e)
    const s16x4 ONES = {(short)0x3F80, (short)0x3F80, (short)0x3F80, (short)0x3F80};

    short8 qfA0, qfA1, qfB0, qfB1;
    {
        const u16* qp = qkv + (baserow + q0 + wid * 32 + r16) * 3072 + h * 64 + g * 8;
        qfA0 = *(const short8*)qp;
        qfA1 = *(const short8*)(qp + 32);
        qfB0 = *(const short8*)(qp + (size_t)16 * 3072);
        qfB1 = *(const short8*)(qp + (size_t)16 * 3072 + 32);
    }

    // per-tile has-mask bitmask (one u32 for all 32 tiles), computed once
    if (tid == 0) tflags_sh = 0;
    __syncthreads();
    for (int r = 0; r < 8; ++r) {
        int v = mask[baserow + r * 256 + tid];
        unsigned long long bal = __ballot(v != 0);
        if (bal != 0 && lane == 0) atomicOr(&tflags_sh, 1u << (r * 4 + wid));
    }

    const int L = lane;
    const u16* kg0 = qkv + (baserow + wid * 16 + (L >> 3)) * 3072 + 1024 + h * 64 + ((L & 7) ^ (L >> 3)) * 8;
    const u16* kg1 = kg0 + (size_t)8 * 3072;
    const u16* vg0 = qkv + (baserow + wid * 16 + ((L & 31) >> 1)) * 3072 + 2048 + h * 64
                     + ((L >> 5) * 16 + (L & 1) * 8);
    const u16* vg1 = vg0 + 32;
    const unsigned vaddr0 = (unsigned)(unsigned long long)&Vs[0][0] + (unsigned)(r16 * 2 + g * 128);

    // prologue: stage tile 0 into buf 0
    gl_lds16(kg0, &Ks[0][wid * 1024]);
    gl_lds16(kg1, &Ks[0][wid * 1024 + 512]);
    gl_lds16(vg0, &Vs[0][wid * 1024]);
    gl_lds16(vg1, &Vs[0][wid * 1024 + 512]);
    __syncthreads();
    const unsigned tfl = tflags_sh;

    f32x4 OtA[4], OtB[4];
#pragma unroll
    for (int dt = 0; dt < 4; dt++) { OtA[dt] = (f32x4){0.f, 0.f, 0.f, 0.f}; OtB[dt] = (f32x4){0.f, 0.f, 0.f, 0.f}; }
    f32x4 OsumA = (f32x4){0.f, 0.f, 0.f, 0.f}, OsumB = (f32x4){0.f, 0.f, 0.f, 0.f};

    for (int t = 0; t < 32; ++t) {
        const int cur = t & 1, nb = cur ^ 1;
        if (t < 31) {
            const size_t go = (size_t)(t + 1) * 64 * 3072;
            gl_lds16(kg0 + go, &Ks[nb][wid * 1024]);
            gl_lds16(kg1 + go, &Ks[nb][wid * 1024 + 512]);
            gl_lds16(vg0 + go, &Vs[nb][wid * 1024]);
            gl_lds16(vg1 + go, &Vs[nb][wid * 1024 + 512]);
            asm volatile("s_waitcnt vmcnt(4)" ::: "memory");   // tile t landed; t+1 in flight
        } else {
            asm volatile("s_waitcnt vmcnt(0)" ::: "memory");
        }
        SBAR();
        const u16* Kc = &Ks[cur][0];
        const unsigned vaddr = vaddr0 + (unsigned)(cur * 8192);

        // S^T tiles for both q-groups (K fragments shared)
        f32x4 zA[4], zB[4];
        __builtin_amdgcn_s_setprio(1);
#pragma unroll
        for (int tt = 0; tt < 4; tt++) {
            const int row = tt * 16 + r16;
            const int swz = row & 7;
            short8 a0 = *(const short8*)&Kc[row * 64 + ((g ^ swz) * 8)];
            short8 a1 = *(const short8*)&Kc[row * 64 + (((4 + g) ^ swz) * 8)];
            f32x4 za = (f32x4){0.f, 0.f, 0.f, 0.f};
            za = MFMA32(a0, qfA0, za);
            za = MFMA32(a1, qfA1, za);
            zA[tt] = za;
            f32x4 zb = (f32x4){0.f, 0.f, 0.f, 0.f};
            zb = MFMA32(a0, qfB0, zb);
            zb = MFMA32(a1, qfB1, zb);
            zB[tt] = zb;
        }
        __builtin_amdgcn_s_setprio(0);

        // p = 2^(z*SCALE [+ mb]) — static zero shift; no max tracking
        s16x4 pbA[4], pbB[4];
        if (__builtin_expect((tfl >> t) & 1u, 0)) {
            const int* mrow = mask + baserow + t * 64;
#pragma unroll
            for (int tt = 0; tt < 4; tt++) {
                float pa[4], pbv[4];
#pragma unroll
                for (int j = 0; j < 4; j++) {
                    float mbj = mrow[tt * 16 + g * 4 + j] ? MNEG : 0.0f;
                    pa[j] = exp2f(__builtin_fmaf(zA[tt][j], SCALE, mbj));
                    pbv[j] = exp2f(__builtin_fmaf(zB[tt][j], SCALE, mbj));
                }
                unsigned lo, hi;
                asm("v_cvt_pk_bf16_f32 %0, %1, %2" : "=v"(lo) : "v"(pa[0]), "v"(pa[1]));
                asm("v_cvt_pk_bf16_f32 %0, %1, %2" : "=v"(hi) : "v"(pa[2]), "v"(pa[3]));
                uint2 ua; ua.x = lo; ua.y = hi;
                pbA[tt] = __builtin_bit_cast(s16x4, ua);
                asm("v_cvt_pk_bf16_f32 %0, %1, %2" : "=v"(lo) : "v"(pbv[0]), "v"(pbv[1]));
                asm("v_cvt_pk_bf16_f32 %0, %1, %2" : "=v"(hi) : "v"(pbv[2]), "v"(pbv[3]));
                uint2 ub; ub.x = lo; ub.y = hi;
                pbB[tt] = __builtin_bit_cast(s16x4, ub);
            }
        } else {
#pragma unroll
            for (int tt = 0; tt < 4; tt++) {
                float pa0 = exp2f(zA[tt][0] * SCALE);
                float pa1 = exp2f(zA[tt][1] * SCALE);
                float pa2 = exp2f(zA[tt][2] * SCALE);
                float pa3 = exp2f(zA[tt][3] * SCALE);
                float pb0 = exp2f(zB[tt][0] * SCALE);
                float pb1 = exp2f(zB[tt][1] * SCALE);
                float pb2 = exp2f(zB[tt][2] * SCALE);
                float pb3 = exp2f(zB[tt][3] * SCALE);
                unsigned lo, hi;
                asm("v_cvt_pk_bf16_f32 %0, %1, %2" : "=v"(lo) : "v"(pa0), "v"(pa1));
                asm("v_cvt_pk_bf16_f32 %0, %1, %2" : "=v"(hi) : "v"(pa2), "v"(pa3));
                uint2 ua; ua.x = lo; ua.y = hi;
                pbA[tt] = __builtin_bit_cast(s16x4, ua);
                asm("v_cvt_pk_bf16_f32 %0, %1, %2" : "=v"(lo) : "v"(pb0), "v"(pb1));
                asm("v_cvt_pk_bf16_f32 %0, %1, %2" : "=v"(hi) : "v"(pb2), "v"(pb3));
                uint2 ub; ub.x = lo; ub.y = hi;
                pbB[tt] = __builtin_bit_cast(s16x4, ub);
            }
        }

        // PV, pipelined per key-subtile: tr_read(tt+1) in flight while MFMA(tt) runs
        s16x4 vf[2][4];
#pragma unroll
        for (int dt = 0; dt < 4; dt++)
            asm volatile("ds_read_b64_tr_b16 %0, %1"
                         : "=v"(vf[0][dt]) : "v"(vaddr + (unsigned)(dt * 512)));
#pragma unroll
        for (int tt = 0; tt < 4; tt++) {
            if (tt < 3) {
#pragma unroll
                for (int dt = 0; dt < 4; dt++)
                    asm volatile("ds_read_b64_tr_b16 %0, %1"
                                 : "=v"(vf[(tt + 1) & 1][dt])
                                 : "v"(vaddr + (unsigned)(((tt + 1) * 4 + dt) * 512)));
                asm volatile("s_waitcnt lgkmcnt(4)" ::: "memory");
            } else {
                asm volatile("s_waitcnt lgkmcnt(0)" ::: "memory");
            }
            __builtin_amdgcn_sched_barrier(0);
            __builtin_amdgcn_s_setprio(1);
#pragma unroll
            for (int dt = 0; dt < 4; dt++) {
                OtA[dt] = MFMA16(vf[tt & 1][dt], pbA[tt], OtA[dt]);
                OtB[dt] = MFMA16(vf[tt & 1][dt], pbB[tt], OtB[dt]);
            }
            OsumA = MFMA16(ONES, pbA[tt], OsumA);
            OsumB = MFMA16(ONES, pbB[tt], OsumB);
            __builtin_amdgcn_s_setprio(0);
        }
        SBAR();   // all reads of buf `cur` retired; iteration t+1 overwrites it
    }

    const float rlA = 1.0f / OsumA[0];
    const float rlB = 1.0f / OsumB[0];
    u16* cpA = ctx + (baserow + q0 + wid * 32 + r16) * 1024 + h * 64 + g * 4;
    u16* cpB = cpA + (size_t)16 * 1024;
#pragma unroll
    for (int dt = 0; dt < 4; dt++) {
        ushort4 oa, ob;
        oa.x = f2b(OtA[dt][0] * rlA); oa.y = f2b(OtA[dt][1] * rlA);
        oa.z = f2b(OtA[dt][2] * rlA); oa.w = f2b(OtA[dt][3] * rlA);
        ob.x = f2b(OtB[dt][0] * rlB); ob.y = f2b(OtB[dt][1] * rlB);
        ob.z = f2b(OtB[dt][2] * rlB); ob.w = f2b(OtB[dt][3] * rlB);
        *(ushort4*)(cpA + dt * 16) = oa;
        *(ushort4*)(cpB + dt * 16) = ob;
    }
}

// ---------------- fused residual + layernorm (res optional) ----------------
__global__ __launch_bounds__(256) void ln_kernel(const float* __restrict__ a, const float* __restrict__ res,
                                                 const float* __restrict__ gamma, const float* __restrict__ beta,
                                                 float* __restrict__ outf, u16* __restrict__ outb) {
    const int row = blockIdx.x, tid = threadIdx.x;
    const size_t base = (size_t)row * 1024 + tid * 4;
    float4 va = *(const float4*)(a + base);
    float x0 = va.x, x1 = va.y, x2 = va.z, x3 = va.w;
    if (res) {
        float4 vr = *(const float4*)(res + base);
        x0 += vr.x; x1 += vr.y; x2 += vr.z; x3 += vr.w;
    }
    float s = x0 + x1 + x2 + x3;
    float ss = x0 * x0 + x1 * x1 + x2 * x2 + x3 * x3;
#pragma unroll
    for (int m = 1; m < 64; m <<= 1) { s += __shfl_xor(s, m, 64); ss += __shfl_xor(ss, m, 64); }
    __shared__ float red[8];
    if ((tid & 63) == 0) { red[tid >> 6] = s; red[4 + (tid >> 6)] = ss; }
    __syncthreads();
    s = red[0] + red[1] + red[2] + red[3];
    ss = red[4] + red[5] + red[6] + red[7];
    float mu = s * (1.0f / 1024.0f);
    float var = ss * (1.0f / 1024.0f) - mu * mu;
    float rstd = rsqrtf(var + 1e-5f);
    float4 g4 = *(const float4*)(gamma + tid * 4);
    float4 b4 = *(const float4*)(beta + tid * 4);
    float y0 = (x0 - mu) * rstd * g4.x + b4.x;
    float y1 = (x1 - mu) * rstd * g4.y + b4.y;
    float y2 = (x2 - mu) * rstd * g4.z + b4.z;
    float y3 = (x3 - mu) * rstd * g4.w + b4.w;
    *(float4*)(outf + base) = make_float4(y0, y1, y2, y3);
    if (outb) {
        ushort4 ob;
        ob.x = f2b(y0); ob.y = f2b(y1); ob.z = f2b(y2); ob.w = f2b(y3);
        *(ushort4*)(outb + base) = ob;
    }
}

extern "C" void kernel_launch(void* const* d_in, const int* in_sizes, int n_in, void* d_out, int out_size,
                              void* d_ws, size_t ws_size, hipStream_t stream) {
    const float* x = (const float*)d_in[0];
    const int* mask = (const int*)d_in[1];
    const float* Wq = (const float*)d_in[2];
    const float* bq = (const float*)d_in[3];
    const float* Wk = (const float*)d_in[4];
    const float* bk = (const float*)d_in[5];
    const float* Wv = (const float*)d_in[6];
    const float* bv = (const float*)d_in[7];
    const float* Wo = (const float*)d_in[8];
    const float* bo = (const float*)d_in[9];
    const float* ln1s = (const float*)d_in[10];
    const float* ln1b = (const float*)d_in[11];
    const float* W1 = (const float*)d_in[12];
    const float* b1 = (const float*)d_in[13];
    const float* W2 = (const float*)d_in[14];
    const float* b2 = (const float*)d_in[15];
    const float* ln2s = (const float*)d_in[16];
    const float* ln2b = (const float*)d_in[17];
    float* out = (float*)d_out;
    char* ws = (char*)d_ws;

    const size_t MB = 1024 * 1024;
    u16* XB = (u16*)(ws + 0);                 // x bf16 [8192][1024]
    u16* WTq = (u16*)(ws + 16 * MB);          // [Wq^T;Wk^T;Wv^T] = Bt[3072][1024]
    u16* WTk = WTq + 1024 * 1024;
    u16* WTv = WTk + 1024 * 1024;
    u16* WTo = WTv + 1024 * 1024;             // Wo^T [1024][1024]
    u16* WT1 = WTo + 1024 * 1024;             // W1^T [4096][1024]
    u16* WT2 = WT1 + 4096 * 1024;             // W2^T [1024][4096]
    float* BIAS = (float*)(ws + 40 * MB);
    u16* QKV = (u16*)(ws + 41 * MB);          // [8192][3072] bf16
    u16* CTX = (u16*)(ws + 0);                // [8192][1024] bf16 (reuse XB)
    float* ATT = (float*)(ws + 41 * MB);      // attn_out + x, fp32 (reuse QKV)
    float* Hbuf = (float*)(ws + 73 * MB);
    u16* HB = (u16*)(ws + 105 * MB);
    u16* MLP1 = (u16*)(ws + 121 * MB);        // [8192][4096] bf16
    float* MLP2 = (float*)(ws + 41 * MB);     // mlp2 + h, fp32 (reuse ATT)

    dim3 tb(32, 8);
    cast_bf16<<<8192, 256, 0, stream>>>(x, XB, 8192 * 1024);
    transpose_cast4<<<dim3(32, 32, 4), tb, 0, stream>>>(Wq, Wk, Wv, Wo, WTq, WTk, WTv, WTo);
    transpose_cast<<<dim3(128, 32), tb, 0, stream>>>(W1, WT1, 1024, 4096);
    transpose_cast<<<dim3(32, 128), tb, 0, stream>>>(W2, WT2, 4096, 1024);
    pack_bias<<<36, 256, 0, stream>>>(bq, bk, bv, bo, b1, b2, BIAS);

    // QKV projection: [8192][3072]
    gemm_bt<128, false, true, false><<<dim3(64, 24), 256, 0, stream>>>(XB, WTq, BIAS, nullptr, QKV, nullptr, 8192, 3072, 1024);
    attn_kernel<<<1024, 256, 0, stream>>>(QKV, mask, CTX);
    // output projection + residual x (fp32 out): BM=64 -> 1024 blocks
    gemm_bt<64, false, false, true><<<dim3(128, 8), 256, 0, stream>>>(CTX, WTo, BIAS + 3072, ATT, nullptr, x, 8192, 1024, 1024);
    ln_kernel<<<8192, 256, 0, stream>>>(ATT, nullptr, ln1s, ln1b, Hbuf, HB);
    // mlp1 = gelu(h @ W1 + b1)
    gemm_bt<128, true, true, false><<<dim3(64, 32), 256, 0, stream>>>(HB, WT1, BIAS + 4096, nullptr, MLP1, nullptr, 8192, 4096, 1024);
    // mlp2 = mlp1 @ W2 + b2 + h: BM=64 -> 1024 blocks
    gemm_bt<64, false, false, true><<<dim3(128, 8), 256, 0, stream>>>(MLP1, WT2, BIAS + 8192, MLP2, nullptr, Hbuf, 8192, 1024, 4096);
    ln_kernel<<<8192, 256, 0, stream>>>(MLP2, nullptr, ln2s, ln2b, out, nullptr);
}

// Round 18
// 454.869 us; speedup vs baseline: 1.0652x; 1.0652x over previous
//
#include <hip/hip_runtime.h>
#include <hip/hip_bf16.h>

typedef __attribute__((ext_vector_type(8))) short short8;
typedef __attribute__((ext_vector_type(4))) short s16x4;
typedef __attribute__((ext_vector_type(4))) float f32x4;
typedef unsigned short u16;

#define DEV __device__ __forceinline__
#define MFMA32(a, b, c) __builtin_amdgcn_mfma_f32_16x16x32_bf16(a, b, c, 0, 0, 0)
#define MFMA16(a, b, c) __builtin_amdgcn_mfma_f32_16x16x16bf16_1k(a, b, c, 0, 0, 0)
#define SBAR() asm volatile("s_barrier" ::: "memory")

DEV u16 f2b(float f) {
    __hip_bfloat16 h = __float2bfloat16(f);
    return __builtin_bit_cast(unsigned short, h);
}

DEV void gl_lds16(const u16* g, u16* l) {
    __builtin_amdgcn_global_load_lds((const unsigned int*)g, (unsigned int*)l, 16, 0, 0);
}

// ---------------- cast x: fp32 -> bf16 ----------------
__global__ __launch_bounds__(256) void cast_bf16(const float* __restrict__ in, u16* __restrict__ out, int n) {
    int i = (blockIdx.x * 256 + threadIdx.x) * 4;
    if (i < n) {
        float4 v = *(const float4*)(in + i);
        ushort4 o;
        o.x = f2b(v.x); o.y = f2b(v.y); o.z = f2b(v.z); o.w = f2b(v.w);
        *(ushort4*)(out + i) = o;
    }
}

// ---------------- transpose + cast: W[R][C] fp32 -> Wt[C][R] bf16 ----------------
__global__ __launch_bounds__(256) void transpose_cast(const float* __restrict__ in, u16* __restrict__ out,
                                                      int R, int C) {
    __shared__ float t[32][33];
    int bx = blockIdx.x * 32;
    int by = blockIdx.y * 32;
    int tx = threadIdx.x, ty = threadIdx.y;  // (32, 8)
#pragma unroll
    for (int i = 0; i < 32; i += 8) t[ty + i][tx] = in[(size_t)(by + ty + i) * C + bx + tx];
    __syncthreads();
#pragma unroll
    for (int i = 0; i < 32; i += 8) out[(size_t)(bx + ty + i) * R + by + tx] = f2b(t[tx][ty + i]);
}

// ---------------- batched 1024x1024 transpose + cast (4 matrices in one launch) ----------------
__global__ __launch_bounds__(256) void transpose_cast4(const float* __restrict__ w0, const float* __restrict__ w1,
                                                       const float* __restrict__ w2, const float* __restrict__ w3,
                                                       u16* __restrict__ o0, u16* __restrict__ o1,
                                                       u16* __restrict__ o2, u16* __restrict__ o3) {
    const float* in = (blockIdx.z == 0) ? w0 : (blockIdx.z == 1) ? w1 : (blockIdx.z == 2) ? w2 : w3;
    u16* out = (blockIdx.z == 0) ? o0 : (blockIdx.z == 1) ? o1 : (blockIdx.z == 2) ? o2 : o3;
    __shared__ float t[32][33];
    int bx = blockIdx.x * 32;
    int by = blockIdx.y * 32;
    int tx = threadIdx.x, ty = threadIdx.y;  // (32, 8)
#pragma unroll
    for (int i = 0; i < 32; i += 8) t[ty + i][tx] = in[(size_t)(by + ty + i) * 1024 + bx + tx];
    __syncthreads();
#pragma unroll
    for (int i = 0; i < 32; i += 8) out[(size_t)(bx + ty + i) * 1024 + by + tx] = f2b(t[tx][ty + i]);
}

// ---------------- pack biases into one buffer ----------------
__global__ __launch_bounds__(256) void pack_bias(const float* __restrict__ bq, const float* __restrict__ bk,
                                                 const float* __restrict__ bv, const float* __restrict__ bo,
                                                 const float* __restrict__ b1, const float* __restrict__ b2,
                                                 float* __restrict__ out) {
    int i = blockIdx.x * 256 + threadIdx.x;
    if (i >= 9216) return;
    float v;
    if (i < 1024) v = bq[i];
    else if (i < 2048) v = bk[i - 1024];
    else if (i < 3072) v = bv[i - 2048];
    else if (i < 4096) v = bo[i - 3072];
    else if (i < 8192) v = b1[i - 4096];
    else v = b2[i - 8192];
    out[i] = v;
}

// ---------------- GEMM: C[M][N] = A[M][K] * Bt[N][K]^T + bias (+res), optional GELU ----------------
// m97 2-barrier structure, BK=64, BMx128 tile, 256 threads (4 waves, 2x2), G4 XOR swizzle
// both-sides (LDS chunk c of row r holds global chunk c^(r&7)). Default block mapping
// (R17's XCD chunking regressed GEMMs: wrong locality axis -> larger per-XCD L2 set).
template <int BM, bool GELU, bool BF16OUT, bool RESID>
__global__ __launch_bounds__(256) void gemm_bt(const u16* __restrict__ A, const u16* __restrict__ B,
                                               const float* __restrict__ bias, float* __restrict__ cf,
                                               u16* __restrict__ cb, const float* __restrict__ res,
                                               int M, int N, int K) {
    constexpr int MI = BM / 32;   // per-wave M fragments (4 or 2)
    __shared__ __align__(16) u16 As[BM * 64];
    __shared__ __align__(16) u16 Bs[128 * 64];
    const int tid = threadIdx.x;
    const int wid = tid >> 6, lane = tid & 63;
    const int wr = wid >> 1, wc = wid & 1;
    const int m0 = blockIdx.x * BM, n0 = blockIdx.y * 128;
    const int r16 = lane & 15, g = lane >> 4;
    const int sw = r16 & 7;

    f32x4 acc[MI][4];
#pragma unroll
    for (int i = 0; i < MI; i++)
#pragma unroll
        for (int j = 0; j < 4; j++) acc[i][j] = (f32x4){0.f, 0.f, 0.f, 0.f};

    const int srow = tid >> 3;
    const int schunk = (tid & 7) ^ (srow & 7);
    const u16* ga = A + (size_t)(m0 + srow) * K + schunk * 8;
    const u16* gb = B + (size_t)(n0 + srow) * K + schunk * 8;

    for (int kt = 0; kt < K; kt += 64) {
#pragma unroll
        for (int j = 0; j < BM / 32; j++)
            gl_lds16(ga + (size_t)(j * 32) * K + kt, &As[(j * 32 + wid * 8) * 64]);
#pragma unroll
        for (int j = 0; j < 4; j++)
            gl_lds16(gb + (size_t)(j * 32) * K + kt, &Bs[(j * 32 + wid * 8) * 64]);
        __syncthreads();
#pragma unroll
        for (int ks = 0; ks < 2; ks++) {
            short8 af[MI], bfr[4];
#pragma unroll
            for (int i = 0; i < MI; i++) {
                int row = wr * (BM / 2) + i * 16 + r16;
                af[i] = *(const short8*)((const char*)As + row * 128 + (((ks * 4 + g) ^ sw) * 16));
            }
#pragma unroll
            for (int j = 0; j < 4; j++) {
                int row = wc * 64 + j * 16 + r16;
                bfr[j] = *(const short8*)((const char*)Bs + row * 128 + (((ks * 4 + g) ^ sw) * 16));
            }
#pragma unroll
            for (int i = 0; i < MI; i++)
#pragma unroll
                for (int j = 0; j < 4; j++) acc[i][j] = MFMA32(af[i], bfr[j], acc[i][j]);
        }
        __syncthreads();
    }

#pragma unroll
    for (int i = 0; i < MI; i++) {
#pragma unroll
        for (int j = 0; j < 4; j++) {
#pragma unroll
            for (int r = 0; r < 4; r++) {
                int row = m0 + wr * (BM / 2) + i * 16 + g * 4 + r;
                int col = n0 + wc * 64 + j * 16 + r16;
                float v = acc[i][j][r] + bias[col];
                if (RESID) v += res[(size_t)row * N + col];
                if (GELU) v = 0.5f * v * (1.0f + erff(v * 0.70710678118654752f));
                if (BF16OUT) cb[(size_t)row * N + col] = f2b(v);
                else cf[(size_t)row * N + col] = v;
            }
        }
    }
}

// ---------------- flash attention (swapped-QK^T, KBLK=64, 2 q-groups/wave, dbuf K/V) ----------------
// Static-shift softmax (no running max; logits bounded). Double-buffered K/V, counted vmcnt(4).
// 1-D grid 1024, XCD-swizzled: 16 q-blocks of one (b,h) share one XCD's L2 K/V panel
// (measured: FETCH 139 -> 24.7 MB).
__global__ __launch_bounds__(256, 4) void attn_kernel(const u16* __restrict__ qkv, const int* __restrict__ mask,
                                                      u16* __restrict__ ctx) {
    const int tid = threadIdx.x, wid = tid >> 6, lane = tid & 63;
    const int r16 = lane & 15, g = lane >> 4;
    const int id = blockIdx.x;
    const int sid = (id & 7) * 128 + (id >> 3);   // XCD k gets sids [128k, 128k+128)
    const int h = (sid >> 4) & 15, b = sid >> 8;
    const size_t baserow = (size_t)b * 2048;
    const int q0 = (sid & 15) * 128;

    __shared__ __align__(16) u16 Ks[2][64 * 64];
    __shared__ __align__(16) u16 Vs[2][64 * 64];
    __shared__ unsigned tflags_sh;

    const float SCALE = 0.18033688011112042f;   // 0.125 * log2(e)
    const float MNEG = -6.196328018e9f;         // -2^32 * log2(e)
    const s16x4 ONES = {(short)0x3F80, (short)0x3F80, (short)0x3F80, (short)0x3F80};

    short8 qfA0, qfA1, qfB0, qfB1;
    {
        const u16* qp = qkv + (baserow + q0 + wid * 32 + r16) * 3072 + h * 64 + g * 8;
        qfA0 = *(const short8*)qp;
        qfA1 = *(const short8*)(qp + 32);
        qfB0 = *(const short8*)(qp + (size_t)16 * 3072);
        qfB1 = *(const short8*)(qp + (size_t)16 * 3072 + 32);
    }

    // per-tile has-mask bitmask (one u32 for all 32 tiles), computed once
    if (tid == 0) tflags_sh = 0;
    __syncthreads();
    for (int r = 0; r < 8; ++r) {
        int v = mask[baserow + r * 256 + tid];
        unsigned long long bal = __ballot(v != 0);
        if (bal != 0 && lane == 0) atomicOr(&tflags_sh, 1u << (r * 4 + wid));
    }

    const int L = lane;
    const u16* kg0 = qkv + (baserow + wid * 16 + (L >> 3)) * 3072 + 1024 + h * 64 + ((L & 7) ^ (L >> 3)) * 8;
    const u16* kg1 = kg0 + (size_t)8 * 3072;
    const u16* vg0 = qkv + (baserow + wid * 16 + ((L & 31) >> 1)) * 3072 + 2048 + h * 64
                     + ((L >> 5) * 16 + (L & 1) * 8);
    const u16* vg1 = vg0 + 32;
    const unsigned vaddr0 = (unsigned)(unsigned long long)&Vs[0][0] + (unsigned)(r16 * 2 + g * 128);

    // prologue: stage tile 0 into buf 0
    gl_lds16(kg0, &Ks[0][wid * 1024]);
    gl_lds16(kg1, &Ks[0][wid * 1024 + 512]);
    gl_lds16(vg0, &Vs[0][wid * 1024]);
    gl_lds16(vg1, &Vs[0][wid * 1024 + 512]);
    __syncthreads();
    const unsigned tfl = tflags_sh;

    f32x4 OtA[4], OtB[4];
#pragma unroll
    for (int dt = 0; dt < 4; dt++) { OtA[dt] = (f32x4){0.f, 0.f, 0.f, 0.f}; OtB[dt] = (f32x4){0.f, 0.f, 0.f, 0.f}; }
    f32x4 OsumA = (f32x4){0.f, 0.f, 0.f, 0.f}, OsumB = (f32x4){0.f, 0.f, 0.f, 0.f};

    for (int t = 0; t < 32; ++t) {
        const int cur = t & 1, nb = cur ^ 1;
        if (t < 31) {
            const size_t go = (size_t)(t + 1) * 64 * 3072;
            gl_lds16(kg0 + go, &Ks[nb][wid * 1024]);
            gl_lds16(kg1 + go, &Ks[nb][wid * 1024 + 512]);
            gl_lds16(vg0 + go, &Vs[nb][wid * 1024]);
            gl_lds16(vg1 + go, &Vs[nb][wid * 1024 + 512]);
            asm volatile("s_waitcnt vmcnt(4)" ::: "memory");   // tile t landed; t+1 in flight
        } else {
            asm volatile("s_waitcnt vmcnt(0)" ::: "memory");
        }
        SBAR();
        const u16* Kc = &Ks[cur][0];
        const unsigned vaddr = vaddr0 + (unsigned)(cur * 8192);

        // S^T tiles for both q-groups (K fragments shared)
        f32x4 zA[4], zB[4];
        __builtin_amdgcn_s_setprio(1);
#pragma unroll
        for (int tt = 0; tt < 4; tt++) {
            const int row = tt * 16 + r16;
            const int swz = row & 7;
            short8 a0 = *(const short8*)&Kc[row * 64 + ((g ^ swz) * 8)];
            short8 a1 = *(const short8*)&Kc[row * 64 + (((4 + g) ^ swz) * 8)];
            f32x4 za = (f32x4){0.f, 0.f, 0.f, 0.f};
            za = MFMA32(a0, qfA0, za);
            za = MFMA32(a1, qfA1, za);
            zA[tt] = za;
            f32x4 zb = (f32x4){0.f, 0.f, 0.f, 0.f};
            zb = MFMA32(a0, qfB0, zb);
            zb = MFMA32(a1, qfB1, zb);
            zB[tt] = zb;
        }
        __builtin_amdgcn_s_setprio(0);

        // p = 2^(z*SCALE [+ mb]) — static zero shift; no max tracking
        s16x4 pbA[4], pbB[4];
        if (__builtin_expect((tfl >> t) & 1u, 0)) {
            const int* mrow = mask + baserow + t * 64;
#pragma unroll
            for (int tt = 0; tt < 4; tt++) {
                float pa[4], pbv[4];
#pragma unroll
                for (int j = 0; j < 4; j++) {
                    float mbj = mrow[tt * 16 + g * 4 + j] ? MNEG : 0.0f;
                    pa[j] = exp2f(__builtin_fmaf(zA[tt][j], SCALE, mbj));
                    pbv[j] = exp2f(__builtin_fmaf(zB[tt][j], SCALE, mbj));
                }
                unsigned lo, hi;
                asm("v_cvt_pk_bf16_f32 %0, %1, %2" : "=v"(lo) : "v"(pa[0]), "v"(pa[1]));
                asm("v_cvt_pk_bf16_f32 %0, %1, %2" : "=v"(hi) : "v"(pa[2]), "v"(pa[3]));
                uint2 ua; ua.x = lo; ua.y = hi;
                pbA[tt] = __builtin_bit_cast(s16x4, ua);
                asm("v_cvt_pk_bf16_f32 %0, %1, %2" : "=v"(lo) : "v"(pbv[0]), "v"(pbv[1]));
                asm("v_cvt_pk_bf16_f32 %0, %1, %2" : "=v"(hi) : "v"(pbv[2]), "v"(pbv[3]));
                uint2 ub; ub.x = lo; ub.y = hi;
                pbB[tt] = __builtin_bit_cast(s16x4, ub);
            }
        } else {
#pragma unroll
            for (int tt = 0; tt < 4; tt++) {
                float pa0 = exp2f(zA[tt][0] * SCALE);
                float pa1 = exp2f(zA[tt][1] * SCALE);
                float pa2 = exp2f(zA[tt][2] * SCALE);
                float pa3 = exp2f(zA[tt][3] * SCALE);
                float pb0 = exp2f(zB[tt][0] * SCALE);
                float pb1 = exp2f(zB[tt][1] * SCALE);
                float pb2 = exp2f(zB[tt][2] * SCALE);
                float pb3 = exp2f(zB[tt][3] * SCALE);
                unsigned lo, hi;
                asm("v_cvt_pk_bf16_f32 %0, %1, %2" : "=v"(lo) : "v"(pa0), "v"(pa1));
                asm("v_cvt_pk_bf16_f32 %0, %1, %2" : "=v"(hi) : "v"(pa2), "v"(pa3));
                uint2 ua; ua.x = lo; ua.y = hi;
                pbA[tt] = __builtin_bit_cast(s16x4, ua);
                asm("v_cvt_pk_bf16_f32 %0, %1, %2" : "=v"(lo) : "v"(pb0), "v"(pb1));
                asm("v_cvt_pk_bf16_f32 %0, %1, %2" : "=v"(hi) : "v"(pb2), "v"(pb3));
                uint2 ub; ub.x = lo; ub.y = hi;
                pbB[tt] = __builtin_bit_cast(s16x4, ub);
            }
        }

        // PV, pipelined per key-subtile: tr_read(tt+1) in flight while MFMA(tt) runs
        s16x4 vf[2][4];
#pragma unroll
        for (int dt = 0; dt < 4; dt++)
            asm volatile("ds_read_b64_tr_b16 %0, %1"
                         : "=v"(vf[0][dt]) : "v"(vaddr + (unsigned)(dt * 512)));
#pragma unroll
        for (int tt = 0; tt < 4; tt++) {
            if (tt < 3) {
#pragma unroll
                for (int dt = 0; dt < 4; dt++)
                    asm volatile("ds_read_b64_tr_b16 %0, %1"
                                 : "=v"(vf[(tt + 1) & 1][dt])
                                 : "v"(vaddr + (unsigned)(((tt + 1) * 4 + dt) * 512)));
                asm volatile("s_waitcnt lgkmcnt(4)" ::: "memory");
            } else {
                asm volatile("s_waitcnt lgkmcnt(0)" ::: "memory");
            }
            __builtin_amdgcn_sched_barrier(0);
            __builtin_amdgcn_s_setprio(1);
#pragma unroll
            for (int dt = 0; dt < 4; dt++) {
                OtA[dt] = MFMA16(vf[tt & 1][dt], pbA[tt], OtA[dt]);
                OtB[dt] = MFMA16(vf[tt & 1][dt], pbB[tt], OtB[dt]);
            }
            OsumA = MFMA16(ONES, pbA[tt], OsumA);
            OsumB = MFMA16(ONES, pbB[tt], OsumB);
            __builtin_amdgcn_s_setprio(0);
        }
        SBAR();   // all reads of buf `cur` retired; iteration t+1 overwrites it
    }

    const float rlA = 1.0f / OsumA[0];
    const float rlB = 1.0f / OsumB[0];
    u16* cpA = ctx + (baserow + q0 + wid * 32 + r16) * 1024 + h * 64 + g * 4;
    u16* cpB = cpA + (size_t)16 * 1024;
#pragma unroll
    for (int dt = 0; dt < 4; dt++) {
        ushort4 oa, ob;
        oa.x = f2b(OtA[dt][0] * rlA); oa.y = f2b(OtA[dt][1] * rlA);
        oa.z = f2b(OtA[dt][2] * rlA); oa.w = f2b(OtA[dt][3] * rlA);
        ob.x = f2b(OtB[dt][0] * rlB); ob.y = f2b(OtB[dt][1] * rlB);
        ob.z = f2b(OtB[dt][2] * rlB); ob.w = f2b(OtB[dt][3] * rlB);
        *(ushort4*)(cpA + dt * 16) = oa;
        *(ushort4*)(cpB + dt * 16) = ob;
    }
}

// ---------------- fused residual + layernorm (res optional) ----------------
__global__ __launch_bounds__(256) void ln_kernel(const float* __restrict__ a, const float* __restrict__ res,
                                                 const float* __restrict__ gamma, const float* __restrict__ beta,
                                                 float* __restrict__ outf, u16* __restrict__ outb) {
    const int row = blockIdx.x, tid = threadIdx.x;
    const size_t base = (size_t)row * 1024 + tid * 4;
    float4 va = *(const float4*)(a + base);
    float x0 = va.x, x1 = va.y, x2 = va.z, x3 = va.w;
    if (res) {
        float4 vr = *(const float4*)(res + base);
        x0 += vr.x; x1 += vr.y; x2 += vr.z; x3 += vr.w;
    }
    float s = x0 + x1 + x2 + x3;
    float ss = x0 * x0 + x1 * x1 + x2 * x2 + x3 * x3;
#pragma unroll
    for (int m = 1; m < 64; m <<= 1) { s += __shfl_xor(s, m, 64); ss += __shfl_xor(ss, m, 64); }
    __shared__ float red[8];
    if ((tid & 63) == 0) { red[tid >> 6] = s; red[4 + (tid >> 6)] = ss; }
    __syncthreads();
    s = red[0] + red[1] + red[2] + red[3];
    ss = red[4] + red[5] + red[6] + red[7];
    float mu = s * (1.0f / 1024.0f);
    float var = ss * (1.0f / 1024.0f) - mu * mu;
    float rstd = rsqrtf(var + 1e-5f);
    float4 g4 = *(const float4*)(gamma + tid * 4);
    float4 b4 = *(const float4*)(beta + tid * 4);
    float y0 = (x0 - mu) * rstd * g4.x + b4.x;
    float y1 = (x1 - mu) * rstd * g4.y + b4.y;
    float y2 = (x2 - mu) * rstd * g4.z + b4.z;
    float y3 = (x3 - mu) * rstd * g4.w + b4.w;
    *(float4*)(outf + base) = make_float4(y0, y1, y2, y3);
    if (outb) {
        ushort4 ob;
        ob.x = f2b(y0); ob.y = f2b(y1); ob.z = f2b(y2); ob.w = f2b(y3);
        *(ushort4*)(outb + base) = ob;
    }
}

extern "C" void kernel_launch(void* const* d_in, const int* in_sizes, int n_in, void* d_out, int out_size,
                              void* d_ws, size_t ws_size, hipStream_t stream) {
    const float* x = (const float*)d_in[0];
    const int* mask = (const int*)d_in[1];
    const float* Wq = (const float*)d_in[2];
    const float* bq = (const float*)d_in[3];
    const float* Wk = (const float*)d_in[4];
    const float* bk = (const float*)d_in[5];
    const float* Wv = (const float*)d_in[6];
    const float* bv = (const float*)d_in[7];
    const float* Wo = (const float*)d_in[8];
    const float* bo = (const float*)d_in[9];
    const float* ln1s = (const float*)d_in[10];
    const float* ln1b = (const float*)d_in[11];
    const float* W1 = (const float*)d_in[12];
    const float* b1 = (const float*)d_in[13];
    const float* W2 = (const float*)d_in[14];
    const float* b2 = (const float*)d_in[15];
    const float* ln2s = (const float*)d_in[16];
    const float* ln2b = (const float*)d_in[17];
    float* out = (float*)d_out;
    char* ws = (char*)d_ws;

    const size_t MB = 1024 * 1024;
    u16* XB = (u16*)(ws + 0);                 // x bf16 [8192][1024]
    u16* WTq = (u16*)(ws + 16 * MB);          // [Wq^T;Wk^T;Wv^T] = Bt[3072][1024]
    u16* WTk = WTq + 1024 * 1024;
    u16* WTv = WTk + 1024 * 1024;
    u16* WTo = WTv + 1024 * 1024;             // Wo^T [1024][1024]
    u16* WT1 = WTo + 1024 * 1024;             // W1^T [4096][1024]
    u16* WT2 = WT1 + 4096 * 1024;             // W2^T [1024][4096]
    float* BIAS = (float*)(ws + 40 * MB);
    u16* QKV = (u16*)(ws + 41 * MB);          // [8192][3072] bf16
    u16* CTX = (u16*)(ws + 0);                // [8192][1024] bf16 (reuse XB)
    float* ATT = (float*)(ws + 41 * MB);      // attn_out + x, fp32 (reuse QKV)
    float* Hbuf = (float*)(ws + 73 * MB);
    u16* HB = (u16*)(ws + 105 * MB);
    u16* MLP1 = (u16*)(ws + 121 * MB);        // [8192][4096] bf16
    float* MLP2 = (float*)(ws + 41 * MB);     // mlp2 + h, fp32 (reuse ATT)

    dim3 tb(32, 8);
    cast_bf16<<<8192, 256, 0, stream>>>(x, XB, 8192 * 1024);
    transpose_cast4<<<dim3(32, 32, 4), tb, 0, stream>>>(Wq, Wk, Wv, Wo, WTq, WTk, WTv, WTo);
    transpose_cast<<<dim3(128, 32), tb, 0, stream>>>(W1, WT1, 1024, 4096);
    transpose_cast<<<dim3(32, 128), tb, 0, stream>>>(W2, WT2, 4096, 1024);
    pack_bias<<<36, 256, 0, stream>>>(bq, bk, bv, bo, b1, b2, BIAS);

    // QKV projection: [8192][3072]
    gemm_bt<128, false, true, false><<<dim3(64, 24), 256, 0, stream>>>(XB, WTq, BIAS, nullptr, QKV, nullptr, 8192, 3072, 1024);
    attn_kernel<<<1024, 256, 0, stream>>>(QKV, mask, CTX);
    // output projection + residual x (fp32 out): BM=64 -> 1024 blocks
    gemm_bt<64, false, false, true><<<dim3(128, 8), 256, 0, stream>>>(CTX, WTo, BIAS + 3072, ATT, nullptr, x, 8192, 1024, 1024);
    ln_kernel<<<8192, 256, 0, stream>>>(ATT, nullptr, ln1s, ln1b, Hbuf, HB);
    // mlp1 = gelu(h @ W1 + b1)
    gemm_bt<128, true, true, false><<<dim3(64, 32), 256, 0, stream>>>(HB, WT1, BIAS + 4096, nullptr, MLP1, nullptr, 8192, 4096, 1024);
    // mlp2 = mlp1 @ W2 + b2 + h: BM=64 -> 1024 blocks
    gemm_bt<64, false, false, true><<<dim3(128, 8), 256, 0, stream>>>(MLP1, WT2, BIAS + 8192, MLP2, nullptr, Hbuf, 8192, 1024, 4096);
    ln_kernel<<<8192, 256, 0, stream>>>(MLP2, nullptr, ln2s, ln2b, out, nullptr);
}

// Round 19
// 450.304 us; speedup vs baseline: 1.0760x; 1.0101x over previous
//
#include <hip/hip_runtime.h>
#include <hip/hip_bf16.h>

typedef __attribute__((ext_vector_type(8))) short short8;
typedef __attribute__((ext_vector_type(4))) short s16x4;
typedef __attribute__((ext_vector_type(4))) float f32x4;
typedef unsigned short u16;

#define DEV __device__ __forceinline__
#define MFMA32(a, b, c) __builtin_amdgcn_mfma_f32_16x16x32_bf16(a, b, c, 0, 0, 0)
#define MFMA16(a, b, c) __builtin_amdgcn_mfma_f32_16x16x16bf16_1k(a, b, c, 0, 0, 0)
#define SBAR() asm volatile("s_barrier" ::: "memory")

DEV u16 f2b(float f) {
    __hip_bfloat16 h = __float2bfloat16(f);
    return __builtin_bit_cast(unsigned short, h);
}

DEV float b2f(u16 u) {
    __hip_bfloat16 h = __builtin_bit_cast(__hip_bfloat16, u);
    return __bfloat162float(h);
}

DEV void gl_lds16(const u16* g, u16* l) {
    __builtin_amdgcn_global_load_lds((const unsigned int*)g, (unsigned int*)l, 16, 0, 0);
}

// ---------------- cast x: fp32 -> bf16 ----------------
__global__ __launch_bounds__(256) void cast_bf16(const float* __restrict__ in, u16* __restrict__ out, int n) {
    int i = (blockIdx.x * 256 + threadIdx.x) * 4;
    if (i < n) {
        float4 v = *(const float4*)(in + i);
        ushort4 o;
        o.x = f2b(v.x); o.y = f2b(v.y); o.z = f2b(v.z); o.w = f2b(v.w);
        *(ushort4*)(out + i) = o;
    }
}

// ---------------- transpose + cast: W[R][C] fp32 -> Wt[C][R] bf16 ----------------
__global__ __launch_bounds__(256) void transpose_cast(const float* __restrict__ in, u16* __restrict__ out,
                                                      int R, int C) {
    __shared__ float t[32][33];
    int bx = blockIdx.x * 32;
    int by = blockIdx.y * 32;
    int tx = threadIdx.x, ty = threadIdx.y;  // (32, 8)
#pragma unroll
    for (int i = 0; i < 32; i += 8) t[ty + i][tx] = in[(size_t)(by + ty + i) * C + bx + tx];
    __syncthreads();
#pragma unroll
    for (int i = 0; i < 32; i += 8) out[(size_t)(bx + ty + i) * R + by + tx] = f2b(t[tx][ty + i]);
}

// ---------------- batched 1024x1024 transpose + cast (4 matrices in one launch) ----------------
__global__ __launch_bounds__(256) void transpose_cast4(const float* __restrict__ w0, const float* __restrict__ w1,
                                                       const float* __restrict__ w2, const float* __restrict__ w3,
                                                       u16* __restrict__ o0, u16* __restrict__ o1,
                                                       u16* __restrict__ o2, u16* __restrict__ o3) {
    const float* in = (blockIdx.z == 0) ? w0 : (blockIdx.z == 1) ? w1 : (blockIdx.z == 2) ? w2 : w3;
    u16* out = (blockIdx.z == 0) ? o0 : (blockIdx.z == 1) ? o1 : (blockIdx.z == 2) ? o2 : o3;
    __shared__ float t[32][33];
    int bx = blockIdx.x * 32;
    int by = blockIdx.y * 32;
    int tx = threadIdx.x, ty = threadIdx.y;  // (32, 8)
#pragma unroll
    for (int i = 0; i < 32; i += 8) t[ty + i][tx] = in[(size_t)(by + ty + i) * 1024 + bx + tx];
    __syncthreads();
#pragma unroll
    for (int i = 0; i < 32; i += 8) out[(size_t)(bx + ty + i) * 1024 + by + tx] = f2b(t[tx][ty + i]);
}

// ---------------- pack biases into one buffer ----------------
__global__ __launch_bounds__(256) void pack_bias(const float* __restrict__ bq, const float* __restrict__ bk,
                                                 const float* __restrict__ bv, const float* __restrict__ bo,
                                                 const float* __restrict__ b1, const float* __restrict__ b2,
                                                 float* __restrict__ out) {
    int i = blockIdx.x * 256 + threadIdx.x;
    if (i >= 9216) return;
    float v;
    if (i < 1024) v = bq[i];
    else if (i < 2048) v = bk[i - 1024];
    else if (i < 3072) v = bv[i - 2048];
    else if (i < 4096) v = bo[i - 3072];
    else if (i < 8192) v = b1[i - 4096];
    else v = b2[i - 8192];
    out[i] = v;
}

// ---------------- GEMM: C[M][N] = A[M][K] * Bt[N][K]^T + bias (+res fp32|bf16), optional GELU ----------------
// m97 2-barrier structure, BK=64, BMx128 tile, 256 threads (4 waves, 2x2), G4 XOR swizzle
// both-sides (LDS chunk c of row r holds global chunk c^(r&7)). Default block mapping.
template <int BM, bool GELU, bool BF16OUT, int RESID>   // RESID: 0=none, 1=fp32, 2=bf16
__global__ __launch_bounds__(256) void gemm_bt(const u16* __restrict__ A, const u16* __restrict__ B,
                                               const float* __restrict__ bias, float* __restrict__ cf,
                                               u16* __restrict__ cb, const void* __restrict__ res,
                                               int M, int N, int K) {
    constexpr int MI = BM / 32;   // per-wave M fragments (4 or 2)
    __shared__ __align__(16) u16 As[BM * 64];
    __shared__ __align__(16) u16 Bs[128 * 64];
    const int tid = threadIdx.x;
    const int wid = tid >> 6, lane = tid & 63;
    const int wr = wid >> 1, wc = wid & 1;
    const int m0 = blockIdx.x * BM, n0 = blockIdx.y * 128;
    const int r16 = lane & 15, g = lane >> 4;
    const int sw = r16 & 7;

    f32x4 acc[MI][4];
#pragma unroll
    for (int i = 0; i < MI; i++)
#pragma unroll
        for (int j = 0; j < 4; j++) acc[i][j] = (f32x4){0.f, 0.f, 0.f, 0.f};

    const int srow = tid >> 3;
    const int schunk = (tid & 7) ^ (srow & 7);
    const u16* ga = A + (size_t)(m0 + srow) * K + schunk * 8;
    const u16* gb = B + (size_t)(n0 + srow) * K + schunk * 8;

    for (int kt = 0; kt < K; kt += 64) {
#pragma unroll
        for (int j = 0; j < BM / 32; j++)
            gl_lds16(ga + (size_t)(j * 32) * K + kt, &As[(j * 32 + wid * 8) * 64]);
#pragma unroll
        for (int j = 0; j < 4; j++)
            gl_lds16(gb + (size_t)(j * 32) * K + kt, &Bs[(j * 32 + wid * 8) * 64]);
        __syncthreads();
#pragma unroll
        for (int ks = 0; ks < 2; ks++) {
            short8 af[MI], bfr[4];
#pragma unroll
            for (int i = 0; i < MI; i++) {
                int row = wr * (BM / 2) + i * 16 + r16;
                af[i] = *(const short8*)((const char*)As + row * 128 + (((ks * 4 + g) ^ sw) * 16));
            }
#pragma unroll
            for (int j = 0; j < 4; j++) {
                int row = wc * 64 + j * 16 + r16;
                bfr[j] = *(const short8*)((const char*)Bs + row * 128 + (((ks * 4 + g) ^ sw) * 16));
            }
#pragma unroll
            for (int i = 0; i < MI; i++)
#pragma unroll
                for (int j = 0; j < 4; j++) acc[i][j] = MFMA32(af[i], bfr[j], acc[i][j]);
        }
        __syncthreads();
    }

#pragma unroll
    for (int i = 0; i < MI; i++) {
#pragma unroll
        for (int j = 0; j < 4; j++) {
#pragma unroll
            for (int r = 0; r < 4; r++) {
                int row = m0 + wr * (BM / 2) + i * 16 + g * 4 + r;
                int col = n0 + wc * 64 + j * 16 + r16;
                float v = acc[i][j][r] + bias[col];
                if (RESID == 1) v += ((const float*)res)[(size_t)row * N + col];
                if (RESID == 2) v += b2f(((const u16*)res)[(size_t)row * N + col]);
                if (GELU) v = 0.5f * v * (1.0f + erff(v * 0.70710678118654752f));
                if (BF16OUT) cb[(size_t)row * N + col] = f2b(v);
                else cf[(size_t)row * N + col] = v;
            }
        }
    }
}

// ---------------- flash attention (swapped-QK^T, KBLK=64, 2 q-groups/wave, dbuf K/V) ----------------
// Static-shift softmax (no running max; logits bounded). Double-buffered K/V, counted vmcnt(4).
// 1-D grid 1024, XCD-swizzled: 16 q-blocks of one (b,h) share one XCD's L2 K/V panel
// (measured: FETCH 139 -> 24.7 MB).
__global__ __launch_bounds__(256, 4) void attn_kernel(const u16* __restrict__ qkv, const int* __restrict__ mask,
                                                      u16* __restrict__ ctx) {
    const int tid = threadIdx.x, wid = tid >> 6, lane = tid & 63;
    const int r16 = lane & 15, g = lane >> 4;
    const int id = blockIdx.x;
    const int sid = (id & 7) * 128 + (id >> 3);   // XCD k gets sids [128k, 128k+128)
    const int h = (sid >> 4) & 15, b = sid >> 8;
    const size_t baserow = (size_t)b * 2048;
    const int q0 = (sid & 15) * 128;

    __shared__ __align__(16) u16 Ks[2][64 * 64];
    __shared__ __align__(16) u16 Vs[2][64 * 64];
    __shared__ unsigned tflags_sh;

    const float SCALE = 0.18033688011112042f;   // 0.125 * log2(e)
    const float MNEG = -6.196328018e9f;         // -2^32 * log2(e)
    const s16x4 ONES = {(short)0x3F80, (short)0x3F80, (short)0x3F80, (short)0x3F80};

    short8 qfA0, qfA1, qfB0, qfB1;
    {
        const u16* qp = qkv + (baserow + q0 + wid * 32 + r16) * 3072 + h * 64 + g * 8;
        qfA0 = *(const short8*)qp;
        qfA1 = *(const short8*)(qp + 32);
        qfB0 = *(const short8*)(qp + (size_t)16 * 3072);
        qfB1 = *(const short8*)(qp + (size_t)16 * 3072 + 32);
    }

    // per-tile has-mask bitmask (one u32 for all 32 tiles), computed once
    if (tid == 0) tflags_sh = 0;
    __syncthreads();
    for (int r = 0; r < 8; ++r) {
        int v = mask[baserow + r * 256 + tid];
        unsigned long long bal = __ballot(v != 0);
        if (bal != 0 && lane == 0) atomicOr(&tflags_sh, 1u << (r * 4 + wid));
    }

    const int L = lane;
    const u16* kg0 = qkv + (baserow + wid * 16 + (L >> 3)) * 3072 + 1024 + h * 64 + ((L & 7) ^ (L >> 3)) * 8;
    const u16* kg1 = kg0 + (size_t)8 * 3072;
    const u16* vg0 = qkv + (baserow + wid * 16 + ((L & 31) >> 1)) * 3072 + 2048 + h * 64
                     + ((L >> 5) * 16 + (L & 1) * 8);
    const u16* vg1 = vg0 + 32;
    const unsigned vaddr0 = (unsigned)(unsigned long long)&Vs[0][0] + (unsigned)(r16 * 2 + g * 128);

    // prologue: stage tile 0 into buf 0
    gl_lds16(kg0, &Ks[0][wid * 1024]);
    gl_lds16(kg1, &Ks[0][wid * 1024 + 512]);
    gl_lds16(vg0, &Vs[0][wid * 1024]);
    gl_lds16(vg1, &Vs[0][wid * 1024 + 512]);
    __syncthreads();
    const unsigned tfl = tflags_sh;

    f32x4 OtA[4], OtB[4];
#pragma unroll
    for (int dt = 0; dt < 4; dt++) { OtA[dt] = (f32x4){0.f, 0.f, 0.f, 0.f}; OtB[dt] = (f32x4){0.f, 0.f, 0.f, 0.f}; }
    f32x4 OsumA = (f32x4){0.f, 0.f, 0.f, 0.f}, OsumB = (f32x4){0.f, 0.f, 0.f, 0.f};

    for (int t = 0; t < 32; ++t) {
        const int cur = t & 1, nb = cur ^ 1;
        if (t < 31) {
            const size_t go = (size_t)(t + 1) * 64 * 3072;
            gl_lds16(kg0 + go, &Ks[nb][wid * 1024]);
            gl_lds16(kg1 + go, &Ks[nb][wid * 1024 + 512]);
            gl_lds16(vg0 + go, &Vs[nb][wid * 1024]);
            gl_lds16(vg1 + go, &Vs[nb][wid * 1024 + 512]);
            asm volatile("s_waitcnt vmcnt(4)" ::: "memory");   // tile t landed; t+1 in flight
        } else {
            asm volatile("s_waitcnt vmcnt(0)" ::: "memory");
        }
        SBAR();
        const u16* Kc = &Ks[cur][0];
        const unsigned vaddr = vaddr0 + (unsigned)(cur * 8192);

        // S^T tiles for both q-groups (K fragments shared)
        f32x4 zA[4], zB[4];
        __builtin_amdgcn_s_setprio(1);
#pragma unroll
        for (int tt = 0; tt < 4; tt++) {
            const int row = tt * 16 + r16;
            const int swz = row & 7;
            short8 a0 = *(const short8*)&Kc[row * 64 + ((g ^ swz) * 8)];
            short8 a1 = *(const short8*)&Kc[row * 64 + (((4 + g) ^ swz) * 8)];
            f32x4 za = (f32x4){0.f, 0.f, 0.f, 0.f};
            za = MFMA32(a0, qfA0, za);
            za = MFMA32(a1, qfA1, za);
            zA[tt] = za;
            f32x4 zb = (f32x4){0.f, 0.f, 0.f, 0.f};
            zb = MFMA32(a0, qfB0, zb);
            zb = MFMA32(a1, qfB1, zb);
            zB[tt] = zb;
        }
        __builtin_amdgcn_s_setprio(0);

        // p = 2^(z*SCALE [+ mb]) — static zero shift; no max tracking
        s16x4 pbA[4], pbB[4];
        if (__builtin_expect((tfl >> t) & 1u, 0)) {
            const int* mrow = mask + baserow + t * 64;
#pragma unroll
            for (int tt = 0; tt < 4; tt++) {
                float pa[4], pbv[4];
#pragma unroll
                for (int j = 0; j < 4; j++) {
                    float mbj = mrow[tt * 16 + g * 4 + j] ? MNEG : 0.0f;
                    pa[j] = exp2f(__builtin_fmaf(zA[tt][j], SCALE, mbj));
                    pbv[j] = exp2f(__builtin_fmaf(zB[tt][j], SCALE, mbj));
                }
                unsigned lo, hi;
                asm("v_cvt_pk_bf16_f32 %0, %1, %2" : "=v"(lo) : "v"(pa[0]), "v"(pa[1]));
                asm("v_cvt_pk_bf16_f32 %0, %1, %2" : "=v"(hi) : "v"(pa[2]), "v"(pa[3]));
                uint2 ua; ua.x = lo; ua.y = hi;
                pbA[tt] = __builtin_bit_cast(s16x4, ua);
                asm("v_cvt_pk_bf16_f32 %0, %1, %2" : "=v"(lo) : "v"(pbv[0]), "v"(pbv[1]));
                asm("v_cvt_pk_bf16_f32 %0, %1, %2" : "=v"(hi) : "v"(pbv[2]), "v"(pbv[3]));
                uint2 ub; ub.x = lo; ub.y = hi;
                pbB[tt] = __builtin_bit_cast(s16x4, ub);
            }
        } else {
#pragma unroll
            for (int tt = 0; tt < 4; tt++) {
                float pa0 = exp2f(zA[tt][0] * SCALE);
                float pa1 = exp2f(zA[tt][1] * SCALE);
                float pa2 = exp2f(zA[tt][2] * SCALE);
                float pa3 = exp2f(zA[tt][3] * SCALE);
                float pb0 = exp2f(zB[tt][0] * SCALE);
                float pb1 = exp2f(zB[tt][1] * SCALE);
                float pb2 = exp2f(zB[tt][2] * SCALE);
                float pb3 = exp2f(zB[tt][3] * SCALE);
                unsigned lo, hi;
                asm("v_cvt_pk_bf16_f32 %0, %1, %2" : "=v"(lo) : "v"(pa0), "v"(pa1));
                asm("v_cvt_pk_bf16_f32 %0, %1, %2" : "=v"(hi) : "v"(pa2), "v"(pa3));
                uint2 ua; ua.x = lo; ua.y = hi;
                pbA[tt] = __builtin_bit_cast(s16x4, ua);
                asm("v_cvt_pk_bf16_f32 %0, %1, %2" : "=v"(lo) : "v"(pb0), "v"(pb1));
                asm("v_cvt_pk_bf16_f32 %0, %1, %2" : "=v"(hi) : "v"(pb2), "v"(pb3));
                uint2 ub; ub.x = lo; ub.y = hi;
                pbB[tt] = __builtin_bit_cast(s16x4, ub);
            }
        }

        // PV, pipelined per key-subtile: tr_read(tt+1) in flight while MFMA(tt) runs
        s16x4 vf[2][4];
#pragma unroll
        for (int dt = 0; dt < 4; dt++)
            asm volatile("ds_read_b64_tr_b16 %0, %1"
                         : "=v"(vf[0][dt]) : "v"(vaddr + (unsigned)(dt * 512)));
#pragma unroll
        for (int tt = 0; tt < 4; tt++) {
            if (tt < 3) {
#pragma unroll
                for (int dt = 0; dt < 4; dt++)
                    asm volatile("ds_read_b64_tr_b16 %0, %1"
                                 : "=v"(vf[(tt + 1) & 1][dt])
                                 : "v"(vaddr + (unsigned)(((tt + 1) * 4 + dt) * 512)));
                asm volatile("s_waitcnt lgkmcnt(4)" ::: "memory");
            } else {
                asm volatile("s_waitcnt lgkmcnt(0)" ::: "memory");
            }
            __builtin_amdgcn_sched_barrier(0);
            __builtin_amdgcn_s_setprio(1);
#pragma unroll
            for (int dt = 0; dt < 4; dt++) {
                OtA[dt] = MFMA16(vf[tt & 1][dt], pbA[tt], OtA[dt]);
                OtB[dt] = MFMA16(vf[tt & 1][dt], pbB[tt], OtB[dt]);
            }
            OsumA = MFMA16(ONES, pbA[tt], OsumA);
            OsumB = MFMA16(ONES, pbB[tt], OsumB);
            __builtin_amdgcn_s_setprio(0);
        }
        SBAR();   // all reads of buf `cur` retired; iteration t+1 overwrites it
    }

    const float rlA = 1.0f / OsumA[0];
    const float rlB = 1.0f / OsumB[0];
    u16* cpA = ctx + (baserow + q0 + wid * 32 + r16) * 1024 + h * 64 + g * 4;
    u16* cpB = cpA + (size_t)16 * 1024;
#pragma unroll
    for (int dt = 0; dt < 4; dt++) {
        ushort4 oa, ob;
        oa.x = f2b(OtA[dt][0] * rlA); oa.y = f2b(OtA[dt][1] * rlA);
        oa.z = f2b(OtA[dt][2] * rlA); oa.w = f2b(OtA[dt][3] * rlA);
        ob.x = f2b(OtB[dt][0] * rlB); ob.y = f2b(OtB[dt][1] * rlB);
        ob.z = f2b(OtB[dt][2] * rlB); ob.w = f2b(OtB[dt][3] * rlB);
        *(ushort4*)(cpA + dt * 16) = oa;
        *(ushort4*)(cpB + dt * 16) = ob;
    }
}

// ---------------- fused residual + layernorm (res, outf optional) ----------------
__global__ __launch_bounds__(256) void ln_kernel(const float* __restrict__ a, const float* __restrict__ res,
                                                 const float* __restrict__ gamma, const float* __restrict__ beta,
                                                 float* __restrict__ outf, u16* __restrict__ outb) {
    const int row = blockIdx.x, tid = threadIdx.x;
    const size_t base = (size_t)row * 1024 + tid * 4;
    float4 va = *(const float4*)(a + base);
    float x0 = va.x, x1 = va.y, x2 = va.z, x3 = va.w;
    if (res) {
        float4 vr = *(const float4*)(res + base);
        x0 += vr.x; x1 += vr.y; x2 += vr.z; x3 += vr.w;
    }
    float s = x0 + x1 + x2 + x3;
    float ss = x0 * x0 + x1 * x1 + x2 * x2 + x3 * x3;
#pragma unroll
    for (int m = 1; m < 64; m <<= 1) { s += __shfl_xor(s, m, 64); ss += __shfl_xor(ss, m, 64); }
    __shared__ float red[8];
    if ((tid & 63) == 0) { red[tid >> 6] = s; red[4 + (tid >> 6)] = ss; }
    __syncthreads();
    s = red[0] + red[1] + red[2] + red[3];
    ss = red[4] + red[5] + red[6] + red[7];
    float mu = s * (1.0f / 1024.0f);
    float var = ss * (1.0f / 1024.0f) - mu * mu;
    float rstd = rsqrtf(var + 1e-5f);
    float4 g4 = *(const float4*)(gamma + tid * 4);
    float4 b4 = *(const float4*)(beta + tid * 4);
    float y0 = (x0 - mu) * rstd * g4.x + b4.x;
    float y1 = (x1 - mu) * rstd * g4.y + b4.y;
    float y2 = (x2 - mu) * rstd * g4.z + b4.z;
    float y3 = (x3 - mu) * rstd * g4.w + b4.w;
    if (outf) *(float4*)(outf + base) = make_float4(y0, y1, y2, y3);
    if (outb) {
        ushort4 ob;
        ob.x = f2b(y0); ob.y = f2b(y1); ob.z = f2b(y2); ob.w = f2b(y3);
        *(ushort4*)(outb + base) = ob;
    }
}

extern "C" void kernel_launch(void* const* d_in, const int* in_sizes, int n_in, void* d_out, int out_size,
                              void* d_ws, size_t ws_size, hipStream_t stream) {
    const float* x = (const float*)d_in[0];
    const int* mask = (const int*)d_in[1];
    const float* Wq = (const float*)d_in[2];
    const float* bq = (const float*)d_in[3];
    const float* Wk = (const float*)d_in[4];
    const float* bk = (const float*)d_in[5];
    const float* Wv = (const float*)d_in[6];
    const float* bv = (const float*)d_in[7];
    const float* Wo = (const float*)d_in[8];
    const float* bo = (const float*)d_in[9];
    const float* ln1s = (const float*)d_in[10];
    const float* ln1b = (const float*)d_in[11];
    const float* W1 = (const float*)d_in[12];
    const float* b1 = (const float*)d_in[13];
    const float* W2 = (const float*)d_in[14];
    const float* b2 = (const float*)d_in[15];
    const float* ln2s = (const float*)d_in[16];
    const float* ln2b = (const float*)d_in[17];
    float* out = (float*)d_out;
    char* ws = (char*)d_ws;

    const size_t MB = 1024 * 1024;
    u16* XB = (u16*)(ws + 0);                 // x bf16 [8192][1024]
    u16* WTq = (u16*)(ws + 16 * MB);          // [Wq^T;Wk^T;Wv^T] = Bt[3072][1024]
    u16* WTk = WTq + 1024 * 1024;
    u16* WTv = WTk + 1024 * 1024;
    u16* WTo = WTv + 1024 * 1024;             // Wo^T [1024][1024]
    u16* WT1 = WTo + 1024 * 1024;             // W1^T [4096][1024]
    u16* WT2 = WT1 + 4096 * 1024;             // W2^T [1024][4096]
    float* BIAS = (float*)(ws + 40 * MB);
    u16* QKV = (u16*)(ws + 41 * MB);          // [8192][3072] bf16
    u16* CTX = (u16*)(ws + 0);                // [8192][1024] bf16 (reuse XB)
    float* ATT = (float*)(ws + 41 * MB);      // attn_out + x, fp32 (reuse QKV)
    u16* HB = (u16*)(ws + 105 * MB);          // h bf16 (only copy of h)
    u16* MLP1 = (u16*)(ws + 121 * MB);        // [8192][4096] bf16
    float* MLP2 = (float*)(ws + 73 * MB);     // mlp2 + h, fp32

    dim3 tb(32, 8);
    cast_bf16<<<8192, 256, 0, stream>>>(x, XB, 8192 * 1024);
    transpose_cast4<<<dim3(32, 32, 4), tb, 0, stream>>>(Wq, Wk, Wv, Wo, WTq, WTk, WTv, WTo);
    transpose_cast<<<dim3(128, 32), tb, 0, stream>>>(W1, WT1, 1024, 4096);
    transpose_cast<<<dim3(32, 128), tb, 0, stream>>>(W2, WT2, 4096, 1024);
    pack_bias<<<36, 256, 0, stream>>>(bq, bk, bv, bo, b1, b2, BIAS);

    // QKV projection: [8192][3072]
    gemm_bt<128, false, true, 0><<<dim3(64, 24), 256, 0, stream>>>(XB, WTq, BIAS, nullptr, QKV, nullptr, 8192, 3072, 1024);
    attn_kernel<<<1024, 256, 0, stream>>>(QKV, mask, CTX);
    // output projection + residual x (fp32 res, fp32 out): BM=64 -> 1024 blocks
    gemm_bt<64, false, false, 1><<<dim3(128, 8), 256, 0, stream>>>(CTX, WTo, BIAS + 3072, ATT, nullptr, x, 8192, 1024, 1024);
    // h = LN(attn_out + x): bf16 only (MLP2 residual reads bf16 h)
    ln_kernel<<<8192, 256, 0, stream>>>(ATT, nullptr, ln1s, ln1b, nullptr, HB);
    // mlp1 = gelu(h @ W1 + b1)
    gemm_bt<128, true, true, 0><<<dim3(64, 32), 256, 0, stream>>>(HB, WT1, BIAS + 4096, nullptr, MLP1, nullptr, 8192, 4096, 1024);
    // mlp2 = mlp1 @ W2 + b2 + h (bf16 res): BM=64 -> 1024 blocks
    gemm_bt<64, false, false, 2><<<dim3(128, 8), 256, 0, stream>>>(MLP1, WT2, BIAS + 8192, MLP2, nullptr, HB, 8192, 1024, 4096);
    ln_kernel<<<8192, 256, 0, stream>>>(MLP2, nullptr, ln2s, ln2b, out, nullptr);
}